// Round 1
// baseline (234.953 us; speedup 1.0000x reference)
//
#include <hip/hip_runtime.h>
#include <hip/hip_bf16.h>

typedef __bf16 bf16_t;
typedef __bf16 bf16x8 __attribute__((ext_vector_type(8)));
typedef __bf16 bf16x4 __attribute__((ext_vector_type(4)));
typedef float f32x4 __attribute__((ext_vector_type(4)));

#define B_N 32
#define T_N 2048
#define C_N 256
#define F_N 1024
#define NSPLIT 16
#define TSUB (T_N / NSPLIT)   // 128

// ---------- transpose + f32->bf16 convert: in[R][Cc] -> outT[Cc][R] ----------
__global__ __launch_bounds__(256) void k_transpose_cvt(
    const float* __restrict__ in, bf16_t* __restrict__ outT, int R, int Cc) {
  __shared__ float tile[32][33];
  const int t = threadIdx.x;
  const int tx = t & 31, ty = t >> 5;            // 32 x 8
  const int tiles_c = Cc >> 5;
  const int tc = blockIdx.x % tiles_c, tr = blockIdx.x / tiles_c;
  const int r0 = tr << 5, c0 = tc << 5;
#pragma unroll
  for (int j = 0; j < 32; j += 8)
    tile[ty + j][tx] = in[(size_t)(r0 + ty + j) * Cc + (c0 + tx)];
  __syncthreads();
#pragma unroll
  for (int j = 0; j < 32; j += 8)
    outT[(size_t)(c0 + ty + j) * R + (r0 + tx)] = (bf16_t)tile[tx][ty + j];
}

// ---------- stats pass 1: partial sum / sumsq over a T-slice ----------
__global__ __launch_bounds__(256) void k_stats_partial(
    const float* __restrict__ x, float* __restrict__ psum, float* __restrict__ psq) {
  const int blk = blockIdx.x;                 // b * NSPLIT + s
  const int b = blk / NSPLIT, s = blk % NSPLIT;
  const int tid = threadIdx.x;
  const int c4 = (tid & 63) << 2;
  const int tg = tid >> 6;                    // 0..3
  const float* xb = x + ((size_t)b * T_N + (size_t)s * TSUB) * C_N;
  f32x4 sum = {0.f, 0.f, 0.f, 0.f};
  f32x4 sq  = {0.f, 0.f, 0.f, 0.f};
#pragma unroll 4
  for (int i = 0; i < TSUB / 4; ++i) {
    const int t = tg + (i << 2);
    f32x4 v = *(const f32x4*)(xb + (size_t)t * C_N + c4);
    sum += v;
    sq += v * v;
  }
  __shared__ f32x4 ls[256];
  __shared__ f32x4 lq[256];
  ls[tid] = sum; lq[tid] = sq;
  __syncthreads();
  if (tid < 64) {
    f32x4 S = ls[tid] + ls[tid + 64] + ls[tid + 128] + ls[tid + 192];
    f32x4 Q = lq[tid] + lq[tid + 64] + lq[tid + 128] + lq[tid + 192];
    *(f32x4*)(psum + (size_t)blk * C_N + c4) = S;
    *(f32x4*)(psq  + (size_t)blk * C_N + c4) = Q;
  }
}

// ---------- stats pass 2: mean + rstd (unbiased var, ddof=1) ----------
__global__ __launch_bounds__(256) void k_stats_final(
    const float* __restrict__ psum, const float* __restrict__ psq,
    float* __restrict__ meanp, float* __restrict__ rstdp) {
  const int b = blockIdx.x, c = threadIdx.x;
  float S = 0.f, Q = 0.f;
#pragma unroll
  for (int s = 0; s < NSPLIT; ++s) {
    S += psum[(size_t)(b * NSPLIT + s) * C_N + c];
    Q += psq[(size_t)(b * NSPLIT + s) * C_N + c];
  }
  const float mu = S / (float)T_N;
  const float var = (Q - (float)T_N * mu * mu) / (float)(T_N - 1);
  meanp[b * C_N + c] = mu;
  rstdp[b * C_N + c] = rsqrtf(var + 1e-5f);
}

// ---------- fused: normalize -> GEMM1 -> ReLU -> GEMM2 -> +x ----------
__global__ __launch_bounds__(256) void k_ffn(
    const float* __restrict__ x, const float* __restrict__ meanp,
    const float* __restrict__ rstdp, const float* __restrict__ gamma,
    const float* __restrict__ beta, const float* __restrict__ b1,
    const float* __restrict__ b2, const bf16_t* __restrict__ W1T,
    const bf16_t* __restrict__ W2T, float* __restrict__ out) {
  __shared__ __attribute__((aligned(128))) unsigned char hAb[64 * 256 * 2];  // 32KB
  __shared__ __attribute__((aligned(128))) unsigned char a1b[64 * 128 * 2];  // 16KB

  const int tid = threadIdx.x;
  const int wid = tid >> 6;
  const int lane = tid & 63;
  const int l15 = lane & 15;
  const int lk8 = (lane >> 4) << 3;   // k sub-offset: 0,8,16,24
  const int lr4 = (lane >> 4) << 2;   // C/D row sub-offset: 0,4,8,12

  const int row0 = blockIdx.x << 6;   // 64 tokens per block
  const int b = row0 >> 11;           // / T_N
  const float* xblk = x + (size_t)row0 * C_N;

  // ---- stage + normalize x tile into swizzled LDS (bf16) ----
  {
    const int c4 = (tid & 63) << 2;
    const f32x4 mu = *(const f32x4*)(meanp + b * C_N + c4);
    const f32x4 rs = *(const f32x4*)(rstdp + b * C_N + c4);
    const f32x4 g  = *(const f32x4*)(gamma + c4);
    const f32x4 be = *(const f32x4*)(beta + c4);
    const int rbase = tid >> 6;
#pragma unroll
    for (int j = 0; j < 16; ++j) {
      const int row = rbase + (j << 2);
      f32x4 xv = *(const f32x4*)(xblk + (size_t)row * C_N + c4);
      f32x4 hv = (xv - mu) * rs * g + be;
      bf16x4 hp;
      hp.x = (bf16_t)hv.x; hp.y = (bf16_t)hv.y;
      hp.z = (bf16_t)hv.z; hp.w = (bf16_t)hv.w;
      const int off = ((row << 9) + (c4 << 1)) ^ ((row & 7) << 4);
      *(bf16x4*)(hAb + off) = hp;
    }
  }
  __syncthreads();

  f32x4 accO[4][4];
#pragma unroll
  for (int m = 0; m < 4; ++m)
#pragma unroll
    for (int n = 0; n < 4; ++n) accO[m][n] = (f32x4){0.f, 0.f, 0.f, 0.f};

#pragma unroll 1
  for (int ch = 0; ch < 8; ++ch) {
    // ---- GEMM1: a1[:, wid*32 + n*16 + l15] over hidden chunk of 128 ----
    f32x4 acc1[4][2];
#pragma unroll
    for (int m = 0; m < 4; ++m) {
      acc1[m][0] = (f32x4){0.f, 0.f, 0.f, 0.f};
      acc1[m][1] = (f32x4){0.f, 0.f, 0.f, 0.f};
    }
    const int hcol0 = (ch << 7) + (wid << 5);
#pragma unroll
    for (int ks = 0; ks < 8; ++ks) {
      bf16x8 af[4];
#pragma unroll
      for (int m = 0; m < 4; ++m) {
        const int row = (m << 4) + l15;
        const int off = ((row << 9) + (((ks << 5) + lk8) << 1)) ^ ((row & 7) << 4);
        af[m] = *(const bf16x8*)(hAb + off);
      }
#pragma unroll
      for (int n = 0; n < 2; ++n) {
        const bf16x8 bfr = *(const bf16x8*)(W1T + (size_t)(hcol0 + (n << 4) + l15) * 256 + (ks << 5) + lk8);
#pragma unroll
        for (int m = 0; m < 4; ++m)
          acc1[m][n] = __builtin_amdgcn_mfma_f32_16x16x32_bf16(af[m], bfr, acc1[m][n], 0, 0, 0);
      }
    }

    __syncthreads();  // previous chunk's a1 consumers are done

    // ---- bias + ReLU + store a1 (bf16, swizzled) ----
#pragma unroll
    for (int n = 0; n < 2; ++n) {
      const float b1v = b1[hcol0 + (n << 4) + l15];
      const int col = (wid << 5) + (n << 4) + l15;
#pragma unroll
      for (int m = 0; m < 4; ++m) {
#pragma unroll
        for (int r = 0; r < 4; ++r) {
          float v = acc1[m][n][r] + b1v;
          v = v > 0.f ? v : 0.f;
          const int row = (m << 4) + lr4 + r;
          const int off = ((row << 8) + (col << 1)) ^ ((row & 7) << 4);
          *(bf16_t*)(a1b + off) = (bf16_t)v;
        }
      }
    }
    __syncthreads();

    // ---- GEMM2: accO += a1 @ W2[chunk, wid*64 + n*16 + l15] ----
#pragma unroll
    for (int ks = 0; ks < 4; ++ks) {
      bf16x8 af[4];
#pragma unroll
      for (int m = 0; m < 4; ++m) {
        const int row = (m << 4) + l15;
        const int off = ((row << 8) + (((ks << 5) + lk8) << 1)) ^ ((row & 7) << 4);
        af[m] = *(const bf16x8*)(a1b + off);
      }
#pragma unroll
      for (int n = 0; n < 4; ++n) {
        const bf16x8 bfr = *(const bf16x8*)(W2T + (size_t)((wid << 6) + (n << 4) + l15) * 1024 + (ch << 7) + (ks << 5) + lk8);
#pragma unroll
        for (int m = 0; m < 4; ++m)
          accO[m][n] = __builtin_amdgcn_mfma_f32_16x16x32_bf16(af[m], bfr, accO[m][n], 0, 0, 0);
      }
    }
  }

  // ---- epilogue: out = accO + b2 + x (residual) ----
#pragma unroll
  for (int n = 0; n < 4; ++n) {
    const int col = (wid << 6) + (n << 4) + l15;
    const float b2v = b2[col];
#pragma unroll
    for (int m = 0; m < 4; ++m) {
      const int rowb = (m << 4) + lr4;
#pragma unroll
      for (int r = 0; r < 4; ++r) {
        const size_t idx = (size_t)(row0 + rowb + r) * C_N + col;
        out[idx] = accO[m][n][r] + b2v + x[idx];
      }
    }
  }
}

extern "C" void kernel_launch(void* const* d_in, const int* in_sizes, int n_in,
                              void* d_out, int out_size, void* d_ws, size_t ws_size,
                              hipStream_t stream) {
  const float* x     = (const float*)d_in[0];
  const float* gamma = (const float*)d_in[1];
  const float* beta  = (const float*)d_in[2];
  const float* W1    = (const float*)d_in[3];
  const float* b1    = (const float*)d_in[4];
  const float* W2    = (const float*)d_in[5];
  const float* b2    = (const float*)d_in[6];
  float* out = (float*)d_out;

  char* ws = (char*)d_ws;
  bf16_t* W1T  = (bf16_t*)ws;                          // [1024][256] bf16, 512KB
  bf16_t* W2T  = (bf16_t*)(ws + (512 << 10));          // [256][1024] bf16, 512KB
  float* psum  = (float*)(ws + (1024 << 10));          // 512KB
  float* psq   = (float*)(ws + (1536 << 10));          // 512KB
  float* meanp = (float*)(ws + (2048 << 10));          // 32KB
  float* rstdp = (float*)(ws + (2048 << 10) + (32 << 10));

  k_transpose_cvt<<<256, 256, 0, stream>>>(W1, W1T, 256, 1024);
  k_transpose_cvt<<<256, 256, 0, stream>>>(W2, W2T, 1024, 256);
  k_stats_partial<<<B_N * NSPLIT, 256, 0, stream>>>(x, psum, psq);
  k_stats_final<<<B_N, 256, 0, stream>>>(psum, psq, meanp, rstdp);
  k_ffn<<<1024, 256, 0, stream>>>(x, meanp, rstdp, gamma, beta, b1, b2, W1T, W2T, out);
}

// Round 2
// 106.538 us; speedup vs baseline: 2.2053x; 2.2053x over previous
//
#include <hip/hip_runtime.h>
#include <hip/hip_bf16.h>

typedef __bf16 bf16_t;
typedef __bf16 bf16x8 __attribute__((ext_vector_type(8)));
typedef float f32x4 __attribute__((ext_vector_type(4)));
typedef float f32x8 __attribute__((ext_vector_type(8)));
typedef float f32x16 __attribute__((ext_vector_type(16)));
typedef unsigned int u32;

#define GAS __attribute__((address_space(1)))
#define LAS __attribute__((address_space(3)))

#define B_N 32
#define T_N 2048
#define C_N 256
#define F_N 1024
#define NSPLIT 16
#define TSUB 128
#define NCHUNK 32
#define CHBYTES 32768

// ---------------- weight prep: build LDS-image layouts in ws ----------------
// W1 image per chunk ch (32 hidden rows): entry (kg 0..31, hl 0..31) 16B =
//   { bf16(W1[kg*8+j][ch*32+hl]) j=0..7 }  at  ch*32768 + kg*512 + hl*16
// W2 image per chunk: entry (G 0..3, cc 0..255) 16B at ch*32768 + 16384 + G*4096 + cc*16
//   element e = bf16(W2[ch*32 + perm(G,e)][cc]),  perm = (e&3) + 8*(2*(G>>1)+(e>>2)) + 4*(G&1)
// perm matches the a1 register order produced by the swapped-GEMM1 C/D layout,
// so GEMM2's A-fragment is just the D1 registers cast to bf16 (no cross-lane).
__global__ __launch_bounds__(256) void k_prep(
    const float* __restrict__ W1, const float* __restrict__ W2,
    bf16_t* __restrict__ wsW) {
  int id = blockIdx.x * 256 + threadIdx.x;
  char* wb = (char*)wsW;
  if (id < 32768) {
    const int kg = id >> 10, h = id & 1023;
    const int ch = h >> 5, hl = h & 31;
    const float* src = W1 + (size_t)(kg << 3) * F_N + h;
    bf16x8 v;
#pragma unroll
    for (int j = 0; j < 8; ++j) v[j] = (bf16_t)src[(size_t)j * F_N];
    *(bf16x8*)(wb + (size_t)ch * CHBYTES + (kg << 9) + (hl << 4)) = v;
  } else {
    id -= 32768;
    const int Hg = id >> 8, cc = id & 255;
    const int ch = Hg >> 2, G = Hg & 3;
    bf16x8 v;
#pragma unroll
    for (int e = 0; e < 8; ++e) {
      const int hid = (ch << 5) + (e & 3) + ((((G >> 1) << 1) + (e >> 2)) << 3) + ((G & 1) << 2);
      v[e] = (bf16_t)W2[(size_t)hid * C_N + cc];
    }
    *(bf16x8*)(wb + (size_t)ch * CHBYTES + 16384 + (G << 12) + (cc << 4)) = v;
  }
}

// ---------------- stats pass 1: partial sum / sumsq over a T-slice ----------------
__global__ __launch_bounds__(256) void k_stats_partial(
    const float* __restrict__ x, float* __restrict__ psum, float* __restrict__ psq) {
  const int blk = blockIdx.x;                 // b * NSPLIT + s
  const int b = blk / NSPLIT, s = blk % NSPLIT;
  const int tid = threadIdx.x;
  const int c4 = (tid & 63) << 2;
  const int tg = tid >> 6;
  const float* xb = x + ((size_t)b * T_N + (size_t)s * TSUB) * C_N;
  f32x4 sum = {0.f, 0.f, 0.f, 0.f};
  f32x4 sq  = {0.f, 0.f, 0.f, 0.f};
#pragma unroll 4
  for (int i = 0; i < TSUB / 4; ++i) {
    const int t = tg + (i << 2);
    f32x4 v = *(const f32x4*)(xb + (size_t)t * C_N + c4);
    sum += v;
    sq += v * v;
  }
  __shared__ f32x4 ls[256];
  __shared__ f32x4 lq[256];
  ls[tid] = sum; lq[tid] = sq;
  __syncthreads();
  if (tid < 64) {
    f32x4 S = ls[tid] + ls[tid + 64] + ls[tid + 128] + ls[tid + 192];
    f32x4 Q = lq[tid] + lq[tid + 64] + lq[tid + 128] + lq[tid + 192];
    *(f32x4*)(psum + (size_t)blk * C_N + c4) = S;
    *(f32x4*)(psq  + (size_t)blk * C_N + c4) = Q;
  }
}

// ---------------- stats pass 2: fused scale/shift (ddof=1) ----------------
__global__ __launch_bounds__(256) void k_stats_final(
    const float* __restrict__ psum, const float* __restrict__ psq,
    const float* __restrict__ gamma, const float* __restrict__ beta,
    float* __restrict__ As, float* __restrict__ Bs) {
  const int b = blockIdx.x, c = threadIdx.x;
  float S = 0.f, Q = 0.f;
#pragma unroll
  for (int s = 0; s < NSPLIT; ++s) {
    S += psum[(size_t)(b * NSPLIT + s) * C_N + c];
    Q += psq[(size_t)(b * NSPLIT + s) * C_N + c];
  }
  const float mu = S / (float)T_N;
  const float var = (Q - (float)T_N * mu * mu) / (float)(T_N - 1);
  const float a = rsqrtf(var + 1e-5f) * gamma[c];
  As[b * C_N + c] = a;
  Bs[b * C_N + c] = beta[c] - mu * a;
}

// ---------------- fused FFN: h->GEMM1->ReLU->GEMM2->+x, all-register activations ----------------
__global__ __launch_bounds__(256, 2) void k_ffn(
    const float* __restrict__ x, const float* __restrict__ As,
    const float* __restrict__ Bs, const float* __restrict__ b1,
    const float* __restrict__ b2, const bf16_t* __restrict__ wsW,
    float* __restrict__ out) {
  __shared__ __attribute__((aligned(128))) unsigned char lds[2][CHBYTES];

  const int tid = threadIdx.x;
  const int lane = tid & 63;
  const int w = tid >> 6;
  const int l31 = lane & 31;
  const int g = lane >> 5;

  const int tok0 = blockIdx.x << 7;       // 128 tokens / block
  const int b = tok0 >> 11;
  const int t0 = tok0 + (w << 5);         // this wave's 32 tokens

  const char* wsb = (const char*)wsW;

  // issue stage of chunk 0 into lds[0] (async, 16B per lane, linear)
#pragma unroll
  for (int j = 0; j < 8; ++j) {
    const int off = (j << 12) + (tid << 4);
    __builtin_amdgcn_global_load_lds((const GAS u32*)(wsb + off),
                                     (LAS u32*)(&lds[0][off]), 16, 0, 0);
  }

  // prologue: normalized h fragments, entirely in registers (64 VGPR)
  bf16x8 hfrag[16];
  {
    const float* xrow = x + (size_t)(t0 + l31) * C_N;
    const float* ar = As + b * C_N;
    const float* br = Bs + b * C_N;
#pragma unroll
    for (int ks = 0; ks < 16; ++ks) {
      const int c0 = (ks << 4) + (g << 3);
      f32x8 xv = *(const f32x8*)(xrow + c0);
      f32x8 av = *(const f32x8*)(ar + c0);
      f32x8 bv = *(const f32x8*)(br + c0);
      f32x8 hv = xv * av + bv;
#pragma unroll
      for (int e = 0; e < 8; ++e) hfrag[ks][e] = (bf16_t)hv[e];
    }
  }

  f32x16 accO[8];
#pragma unroll
  for (int nb = 0; nb < 8; ++nb)
#pragma unroll
    for (int e = 0; e < 16; ++e) accO[nb][e] = 0.f;

  __syncthreads();   // implicit vmcnt(0) drain covers the chunk-0 stage

#pragma unroll 2
  for (int ch = 0; ch < NCHUNK; ++ch) {
    // stage next chunk into the other buffer (latency hidden under compute)
    if (ch + 1 < NCHUNK) {
      const char* gsrc = wsb + (size_t)(ch + 1) * CHBYTES;
      unsigned char* ldst = lds[(ch + 1) & 1];
#pragma unroll
      for (int j = 0; j < 8; ++j) {
        const int off = (j << 12) + (tid << 4);
        __builtin_amdgcn_global_load_lds((const GAS u32*)(gsrc + off),
                                         (LAS u32*)(ldst + off), 16, 0, 0);
      }
    }
    const unsigned char* W1c = lds[ch & 1];
    const unsigned char* W2c = W1c + 16384;

    // GEMM1 (swapped): D1[hid][token] = sum_k W1T[hid][k] * h[token][k]
    f32x16 D1;
#pragma unroll
    for (int e = 0; e < 16; ++e) D1[e] = 0.f;
#pragma unroll
    for (int ks = 0; ks < 16; ++ks) {
      const bf16x8 wf = *(const bf16x8*)(W1c + ((((ks << 1) + g) << 9) + (l31 << 4)));
      D1 = __builtin_amdgcn_mfma_f32_32x32x16_bf16(wf, hfrag[ks], D1, 0, 0, 0);
    }

    // bias + ReLU + cast: a1 reg r holds hid = (r&3)+8*(r>>2)+4g
    const float* b1c = b1 + (ch << 5) + (g << 2);
    f32x4 b1q[4];
#pragma unroll
    for (int q = 0; q < 4; ++q) b1q[q] = *(const f32x4*)(b1c + (q << 3));

    bf16x8 af[2];
#pragma unroll
    for (int r = 0; r < 16; ++r) {
      float v = D1[r] + b1q[r >> 2][r & 3];
      v = v > 0.f ? v : 0.f;
      af[r >> 3][r & 7] = (bf16_t)v;
    }

    // GEMM2: accO[nb] += a1 @ W2 (W2 rows pre-permuted to match af order)
#pragma unroll
    for (int s = 0; s < 2; ++s) {
#pragma unroll
      for (int nb = 0; nb < 8; ++nb) {
        const bf16x8 wf2 = *(const bf16x8*)(W2c + (((s << 1) + g) << 12) + (nb << 9) + (l31 << 4));
        accO[nb] = __builtin_amdgcn_mfma_f32_32x32x16_bf16(af[s], wf2, accO[nb], 0, 0, 0);
      }
    }
    __syncthreads();
  }

  // epilogue: out = accO + b2 + x   (token = 4g + rr + 8q, col = nb*32 + l31)
  {
    const float* xbase = x + (size_t)(t0 + (g << 2)) * C_N;
    float* obase = out + (size_t)(t0 + (g << 2)) * C_N;
#pragma unroll
    for (int nb = 0; nb < 8; ++nb) {
      const int c = (nb << 5) + l31;
      const float b2v = b2[c];
#pragma unroll
      for (int q = 0; q < 4; ++q) {
#pragma unroll
        for (int rr = 0; rr < 4; ++rr) {
          const size_t idx = (size_t)((q << 3) + rr) * C_N + c;
          obase[idx] = accO[nb][(q << 2) + rr] + b2v + xbase[idx];
        }
      }
    }
  }
}

extern "C" void kernel_launch(void* const* d_in, const int* in_sizes, int n_in,
                              void* d_out, int out_size, void* d_ws, size_t ws_size,
                              hipStream_t stream) {
  const float* x     = (const float*)d_in[0];
  const float* gamma = (const float*)d_in[1];
  const float* beta  = (const float*)d_in[2];
  const float* W1    = (const float*)d_in[3];
  const float* b1    = (const float*)d_in[4];
  const float* W2    = (const float*)d_in[5];
  const float* b2    = (const float*)d_in[6];
  float* out = (float*)d_out;

  char* ws = (char*)d_ws;
  bf16_t* wsW  = (bf16_t*)ws;                           // 1 MB (32 chunks x 32KB)
  float* psum  = (float*)(ws + (1024 << 10));           // 512 KB
  float* psq   = (float*)(ws + (1536 << 10));           // 512 KB
  float* As    = (float*)(ws + (2048 << 10));           // 32 KB
  float* Bs    = (float*)(ws + (2048 << 10) + (32 << 10));

  k_prep<<<256, 256, 0, stream>>>(W1, W2, wsW);
  k_stats_partial<<<B_N * NSPLIT, 256, 0, stream>>>(x, psum, psq);
  k_stats_final<<<B_N, 256, 0, stream>>>(psum, psq, gamma, beta, As, Bs);
  k_ffn<<<512, 256, 0, stream>>>(x, As, Bs, b1, b2, wsW, out);
}